// Round 2
// baseline (421.287 us; speedup 1.0000x reference)
//
#include <hip/hip_runtime.h>
#include <hip/hip_bf16.h>

// Problem constants: B=1 T=64 W=88 HP=48 F0=HP+5=53 HL=12 G=4*HL=48
// NU=24 NH=4 HD=6 K=25 half=12  H grid=64(T), W grid=88
// All float tensors are float32 (per reference); condition is int32.
#define NPIX (64*88)          // 5632
#define NSEQ 88               // B*W sequences
#define TT 64                 // timesteps
#define F0 53
#define GATES 48

__device__ __forceinline__ float sigm(float x){ return 1.0f/(1.0f+__expf(-x)); }
__device__ __forceinline__ float tanhfast(float x){ return 2.0f/(1.0f+__expf(-2.0f*x)) - 1.0f; }

// ---------------- Stage A: build LSTM input (88 seqs, 64 steps, 53 feats) ----
// x0[(w*64+t)*53 + f] = f<48: features[0,t,f,w]; f<52: emb[cond[t,w], f-48]; f==52: mask[t,w]
__global__ void k_build_x0(const float* __restrict__ feat, const int* __restrict__ cond,
                           const float* __restrict__ mask, const float* __restrict__ emb,
                           float* __restrict__ x0){
  int tid = blockIdx.x*blockDim.x + threadIdx.x;
  if (tid >= NSEQ*TT*F0) return;
  int f = tid % F0; int r = tid / F0; int t = r % TT; int w = r / TT;
  float v;
  if (f < 48)      v = feat[(t*48 + f)*88 + w];
  else if (f < 52) v = emb[cond[t*88+w]*4 + (f-48)];
  else             v = mask[t*88+w];
  x0[tid] = v;
}

// ---------------- Stage B1: gate precompute  gp[((d*88+n)*64+t)*48+j] -------
__global__ void k_gates(const float* __restrict__ xin, const float* __restrict__ wih,
                        const float* __restrict__ bih, const float* __restrict__ bhh,
                        float* __restrict__ gp, int IN){
  int tid = blockIdx.x*blockDim.x + threadIdx.x;
  if (tid >= 2*NSEQ*TT*GATES) return;
  int j = tid % GATES; int r = tid / GATES;
  int t = r % TT; int n = (r/TT) % NSEQ; int d = r / (TT*NSEQ);
  const float* xr = xin + (n*TT + t)*IN;
  const float* wr = wih + (d*GATES + j)*IN;
  float acc = bih[d*GATES+j] + bhh[d*GATES+j];
  for (int f=0; f<IN; ++f) acc += xr[f]*wr[f];
  gp[tid] = acc;
}

// ---------------- Stage B2: recurrence, one wave per (dir, seq) -------------
// mode 0: yout[(n*64+t)*24 + d*12+j]   (layer0 output, seq-major)
// mode 1: yout[(t*88+n)*24 + d*12+j]   (layer1 output, pixel-major for NATTEN)
__global__ __launch_bounds__(64) void k_lstm_rec(const float* __restrict__ gp,
                          const float* __restrict__ whh,
                          float* __restrict__ yout, int mode){
  int b = blockIdx.x; int d = b / NSEQ; int n = b % NSEQ;
  int lane = threadIdx.x;
  __shared__ float sW[GATES*12];
  __shared__ float h[12], c[12];
  if (lane < GATES){
    #pragma unroll
    for (int m=0;m<12;++m) sW[lane*12+m] = whh[(d*GATES+lane)*12+m];
  }
  if (lane < 12){ h[lane]=0.f; c[lane]=0.f; }
  __syncthreads();
  const float* gpb = gp + (size_t)(d*NSEQ + n)*TT*GATES;
  for (int s=0;s<TT;++s){
    int t = d ? (TT-1-s) : s;
    float g = 0.f;
    if (lane < GATES){
      const float* gr = gpb + t*GATES;
      g = gr[lane];
      #pragma unroll
      for (int m=0;m<12;++m) g += h[m]*sW[lane*12+m];
    }
    float xi = __shfl(g, lane);
    float xf = __shfl(g, lane+12);
    float xg = __shfl(g, lane+24);
    float xo = __shfl(g, lane+36);
    __syncthreads();
    if (lane < 12){
      float cn = sigm(xf)*c[lane] + sigm(xi)*tanhfast(xg);
      float hn = sigm(xo)*tanhfast(cn);
      c[lane]=cn; h[lane]=hn;
      int off = d*12 + lane;
      if (mode==0) yout[(n*TT+t)*24 + off] = hn;
      else         yout[(t*88+n)*24 + off] = hn;
    }
    __syncthreads();
  }
}

// ---------------- Stage C1: qkv projection ----------------------------------
__global__ void k_qkv(const float* __restrict__ xin, const float* __restrict__ qkv_w,
                      const float* __restrict__ qkv_b, float* __restrict__ q,
                      float* __restrict__ k, float* __restrict__ v){
  int tid = blockIdx.x*blockDim.x + threadIdx.x;
  if (tid >= NPIX*72) return;
  int g = tid % 72; int r = tid / 72;
  const float* xr = xin + r*24;
  const float* wr = qkv_w + g*24;
  float acc = qkv_b[g];
  #pragma unroll
  for (int cidx=0; cidx<24; ++cidx) acc += xr[cidx]*wr[cidx];
  int s = g/24, rem = g - s*24;
  if (s==0)      q[r*24+rem] = acc*0.4082482904638631f;   // HD^-0.5 = 1/sqrt(6)
  else if (s==1) k[r*24+rem] = acc;
  else           v[r*24+rem] = acc;
}

// ---------------- Stage C2: neighborhood attention, 1 wave per (pixel,head) -
__global__ __launch_bounds__(64) void k_attn(const float* __restrict__ q,
                      const float* __restrict__ kk, const float* __restrict__ vv,
                      const float* __restrict__ rpb, float* __restrict__ ao){
  int b = blockIdx.x; int h = b & 3; int p = b >> 2;
  int i = p / 88, j = p - (p/88)*88;
  int si = min(max(i-12,0),39), sj = min(max(j-12,0),63);
  int lane = threadIdx.x;
  float qv[6];
  #pragma unroll
  for (int d=0; d<6; ++d) qv[d] = q[p*24 + h*6 + d];
  float lgv[10];
  float lmax = -1e30f;
  #pragma unroll
  for (int it=0; it<10; ++it){
    int nb = lane + it*64;
    float lg = -1e30f;
    if (nb < 625){
      int a = nb/25, cc = nb - a*25;
      int gi = si + a, gj = sj + cc;
      const float* kp = kk + ((gi*88+gj)*24 + h*6);
      lg = qv[0]*kp[0]+qv[1]*kp[1]+qv[2]*kp[2]+qv[3]*kp[3]+qv[4]*kp[4]+qv[5]*kp[5];
      lg += rpb[(h*49 + (gi - i + 24))*49 + (gj - j + 24)];
    }
    lgv[it] = lg;
    lmax = fmaxf(lmax, lg);
  }
  #pragma unroll
  for (int off=32; off; off>>=1) lmax = fmaxf(lmax, __shfl_xor(lmax, off));
  float lsum = 0.f;
  #pragma unroll
  for (int it=0; it<10; ++it){
    float pe = (lgv[it] > -1e29f) ? __expf(lgv[it]-lmax) : 0.f;
    lgv[it] = pe; lsum += pe;
  }
  #pragma unroll
  for (int off=32; off; off>>=1) lsum += __shfl_xor(lsum, off);
  float acc[6] = {0,0,0,0,0,0};
  #pragma unroll
  for (int it=0; it<10; ++it){
    int nb = lane + it*64;
    if (nb < 625){
      int a = nb/25, cc = nb - a*25;
      int gi = si + a, gj = sj + cc;
      const float* vp = vv + ((gi*88+gj)*24 + h*6);
      float pe = lgv[it];
      #pragma unroll
      for (int d=0; d<6; ++d) acc[d] += pe*vp[d];
    }
  }
  #pragma unroll
  for (int d=0; d<6; ++d){
    #pragma unroll
    for (int off=32; off; off>>=1) acc[d] += __shfl_xor(acc[d], off);
  }
  if (lane == 0){
    float inv = 1.f/lsum;
    #pragma unroll
    for (int d=0; d<6; ++d) ao[p*24 + h*6 + d] = acc[d]*inv;
  }
}

// ---------------- Stage C3: output projection (back into x) -----------------
__global__ void k_proj(const float* __restrict__ ain, const float* __restrict__ pw,
                       const float* __restrict__ pb, float* __restrict__ yout){
  int tid = blockIdx.x*blockDim.x + threadIdx.x;
  if (tid >= NPIX*24) return;
  int o = tid % 24; int r = tid / 24;
  const float* xr = ain + r*24;
  const float* wr = pw + o*24;
  float acc = pb[o];
  #pragma unroll
  for (int cidx=0; cidx<24; ++cidx) acc += xr[cidx]*wr[cidx];
  yout[tid] = acc;
}

// ---------------- Stage D: final 24->5 head ---------------------------------
__global__ void k_out(const float* __restrict__ xin, const float* __restrict__ ow,
                      const float* __restrict__ ob, float* __restrict__ out){
  int tid = blockIdx.x*blockDim.x + threadIdx.x;
  if (tid >= NPIX*5) return;
  int o = tid % 5; int r = tid / 5;
  const float* xr = xin + r*24;
  const float* wr = ow + o*24;
  float acc = ob[o];
  #pragma unroll
  for (int cidx=0; cidx<24; ++cidx) acc += xr[cidx]*wr[cidx];
  out[tid] = acc;
}

extern "C" void kernel_launch(void* const* d_in, const int* in_sizes, int n_in,
                              void* d_out, int out_size, void* d_ws, size_t ws_size,
                              hipStream_t stream) {
  const float* feat    = (const float*)d_in[0];
  const int*   cond    = (const int*)  d_in[1];
  const float* mask    = (const float*)d_in[2];
  const float* emb     = (const float*)d_in[3];
  const float* w_ih_l0 = (const float*)d_in[4];
  const float* w_hh_l0 = (const float*)d_in[5];
  const float* b_ih_l0 = (const float*)d_in[6];
  const float* b_hh_l0 = (const float*)d_in[7];
  const float* w_ih_l1 = (const float*)d_in[8];
  const float* w_hh_l1 = (const float*)d_in[9];
  const float* b_ih_l1 = (const float*)d_in[10];
  const float* b_hh_l1 = (const float*)d_in[11];
  const float* qkv_w   = (const float*)d_in[12];
  const float* qkv_b   = (const float*)d_in[13];
  const float* rpb     = (const float*)d_in[14];
  const float* proj_w  = (const float*)d_in[15];
  const float* proj_b  = (const float*)d_in[16];
  const float* out_w   = (const float*)d_in[17];
  const float* out_b   = (const float*)d_in[18];
  float* out = (float*)d_out;

  float* ws = (float*)d_ws;
  float* X0 = ws;               // 5632*53   = 298496
  float* GP = X0 + 298496;      // 2*5632*48 = 540672 (reused by both layers)
  float* Y0 = GP + 540672;      // 5632*24   = 135168
  float* XA = Y0 + 135168;      // 135168 (pixel-major x for attention)
  float* Q  = XA + 135168;      // 135168
  float* Kb = Q  + 135168;      // 135168
  float* Vb = Kb + 135168;      // 135168
  float* AO = Vb + 135168;      // 135168

  k_build_x0<<<(NSEQ*TT*F0 + 255)/256, 256, 0, stream>>>(feat, cond, mask, emb, X0);

  // LSTM layer 0
  k_gates<<<(2*NSEQ*TT*GATES + 255)/256, 256, 0, stream>>>(X0, w_ih_l0, b_ih_l0, b_hh_l0, GP, F0);
  k_lstm_rec<<<2*NSEQ, 64, 0, stream>>>(GP, w_hh_l0, Y0, 0);
  // LSTM layer 1 (input = 24-dim y0), output directly in pixel-major layout
  k_gates<<<(2*NSEQ*TT*GATES + 255)/256, 256, 0, stream>>>(Y0, w_ih_l1, b_ih_l1, b_hh_l1, GP, 24);
  k_lstm_rec<<<2*NSEQ, 64, 0, stream>>>(GP, w_hh_l1, XA, 1);

  // Two NATTEN layers (same weights, applied twice)
  for (int l=0; l<2; ++l){
    k_qkv <<<(NPIX*72 + 255)/256, 256, 0, stream>>>(XA, qkv_w, qkv_b, Q, Kb, Vb);
    k_attn<<<NPIX*4, 64, 0, stream>>>(Q, Kb, Vb, rpb, AO);
    k_proj<<<(NPIX*24 + 255)/256, 256, 0, stream>>>(AO, proj_w, proj_b, XA);
  }

  k_out<<<(NPIX*5 + 255)/256, 256, 0, stream>>>(XA, out_w, out_b, out);
}